// Round 4
// baseline (670.741 us; speedup 1.0000x reference)
//
#include <hip/hip_runtime.h>
#include <hip/hip_bf16.h>

#define NNODES 50000
#define NEDGES 600000
#define NGRAPHS 128
#define EMB 128
#define NLAYERS 5
#define BN_EPS 1e-5f
#define SCAN_BLOCKS ((NNODES + 255) / 256)    // 196
#define NSB ((NNODES + 255) / 256)            // 196 node_S_bond blocks
#define EAB ((NNODES + 31) / 32)              // 1563 enc_atom blocks
#define BPB ((NLAYERS * 32768 + 255) / 256)   // 640 bprep blocks

typedef short s16x8 __attribute__((ext_vector_type(8)));
typedef float f32x16 __attribute__((ext_vector_type(16)));

__device__ __forceinline__ short f2bf(float f) {
    unsigned u = __builtin_bit_cast(unsigned, f);
    unsigned r = (u + 0x7fffu + ((u >> 16) & 1u)) >> 16;  // RNE
    return (short)r;
}
__device__ __forceinline__ float bf2f(short s) {
    return __builtin_bit_cast(float, ((unsigned)(unsigned short)s) << 16);
}

// ---------------- init: zero pool region, deg, stat (replaces 3 memsets) -----
__global__ __launch_bounds__(256) void init_kernel(float* __restrict__ pool,
                                                   int* __restrict__ deg,
                                                   float* __restrict__ stat) {
    int i = blockIdx.x * 256 + threadIdx.x;
    if (i < NGRAPHS * 640) pool[i] = 0.f;
    if (i < NNODES) deg[i] = 0;
    if (i < NLAYERS * 256) stat[i] = 0.f;
}

// ---------------- deg histogram (int atomics only) ---------------------------
__global__ __launch_bounds__(256) void deg_kernel(const int* __restrict__ ei,
                                                  int* __restrict__ deg) {
    int e = blockIdx.x * 256 + threadIdx.x;
    if (e >= NEDGES) return;
    atomicAdd(&deg[ei[NEDGES + e]], 1);
}

// ---------------- multi-block scan (3 fast dispatches) -----------------------
__global__ __launch_bounds__(256) void scan1(const int* __restrict__ deg,
                                             int* __restrict__ local_excl,
                                             int* __restrict__ part) {
    __shared__ int sh[256];
    int t = threadIdx.x;
    int i = blockIdx.x * 256 + t;
    int v = (i < NNODES) ? deg[i] : 0;
    sh[t] = v;
    __syncthreads();
    for (int off = 1; off < 256; off <<= 1) {
        int u = (t >= off) ? sh[t - off] : 0;
        __syncthreads();
        sh[t] += u;
        __syncthreads();
    }
    if (i < NNODES) local_excl[i] = sh[t] - v;
    if (t == 255) part[blockIdx.x] = sh[255];
}

__global__ __launch_bounds__(256) void scan2(int* __restrict__ part,
                                             int* __restrict__ blockoff,
                                             int* __restrict__ rowptr) {
    __shared__ int sh[256];
    int t = threadIdx.x;
    int v = (t < SCAN_BLOCKS) ? part[t] : 0;
    sh[t] = v;
    __syncthreads();
    for (int off = 1; off < 256; off <<= 1) {
        int u = (t >= off) ? sh[t - off] : 0;
        __syncthreads();
        sh[t] += u;
        __syncthreads();
    }
    if (t < SCAN_BLOCKS) blockoff[t] = sh[t] - v;
    if (t == 255) rowptr[NNODES] = sh[255];
}

__global__ __launch_bounds__(256) void scan3(const int* __restrict__ local_excl,
                                             const int* __restrict__ blockoff,
                                             int* __restrict__ rowptr,
                                             int* __restrict__ cursor) {
    int i = blockIdx.x * 256 + threadIdx.x;
    if (i >= NNODES) return;
    int v = local_excl[i] + blockoff[blockIdx.x];
    rowptr[i] = v;
    cursor[i] = v;
}

// ---------------- fill CSR: 32B record {src, w, 11x bf16 attr, pad} ----------
__global__ __launch_bounds__(256) void edge_fill(const int* __restrict__ ei,
                                                 const float* __restrict__ ew,
                                                 const float* __restrict__ eattr,
                                                 int* __restrict__ cursor,
                                                 int* __restrict__ epk) {
    int e = blockIdx.x * 256 + threadIdx.x;
    if (e >= NEDGES) return;
    int src = ei[e];
    int dst = ei[NEDGES + e];
    int pos = atomicAdd(&cursor[dst], 1);
    int pk[8];
    pk[0] = src;
    pk[1] = __float_as_int(ew[e]);
    unsigned short a[12];
#pragma unroll
    for (int j = 0; j < 11; j++) a[j] = (unsigned short)f2bf(eattr[e * 11 + j]);
    a[11] = 0;
#pragma unroll
    for (int j = 0; j < 6; j++)
        pk[2 + j] = (int)a[2 * j] | ((int)a[2 * j + 1] << 16);
    int* dstp = epk + (size_t)pos * 8;
    *(int4*)dstp = *(int4*)pk;
    *(int4*)(dstp + 4) = *(int4*)(pk + 4);
}

// ---------------- prep2: heterogeneous {node_S+enc_bond | enc_atom | bprep} --
__global__ __launch_bounds__(256) void prep2(const int* __restrict__ rowptr,
                                             const int* __restrict__ epk,
                                             int2* __restrict__ epg,
                                             const float* __restrict__ Wb,
                                             const float* __restrict__ bbond,
                                             short* __restrict__ Ehi,
                                             const float* __restrict__ X,
                                             const float* __restrict__ Wa,
                                             const float* __restrict__ ba,
                                             short* __restrict__ Hhi,
                                             const float* __restrict__ Wl,
                                             const float* __restrict__ Wr,
                                             short* __restrict__ Bf) {
    __shared__ float shpool[1792];  // 7168 B, aliased by branches
    int blk = blockIdx.x;
    int t = threadIdx.x;

    if (blk < NSB) {
        // ---- node_S + enc_bond fused: thread-per-node ----
        float* Wb_s = shpool;        // 11*128 = 1408
        float* bb_s = shpool + 1408; // 128
        for (int i = t; i < 1408; i += 256) Wb_s[i] = Wb[i];
        if (t < 128) bb_s[t] = bbond[t];
        __syncthreads();
        int node = blk * 256 + t;
        if (node >= NNODES) return;
        int b = rowptr[node], e = rowptr[node + 1];
        float s[11];
#pragma unroll
        for (int j = 0; j < 11; j++) s[j] = 0.f;
        float ws = 0.f;
        for (int p = b; p < e; p++) {
            const int* pk = epk + (size_t)p * 8;
            int4 lo = *(const int4*)pk;
            int4 hi = *(const int4*)(pk + 4);
            float w = __int_as_float(lo.y);
            ws += w;
            epg[p] = make_int2(lo.x, lo.y);   // compact {src,w} gather record
            int packed[6] = {lo.z, lo.w, hi.x, hi.y, hi.z, hi.w};
#pragma unroll
            for (int j = 0; j < 11; j++) {
                short v = (short)((packed[j >> 1] >> ((j & 1) * 16)) & 0xffff);
                s[j] += bf2f(v) * w;
            }
        }
        short* erow = Ehi + (size_t)node * 128;
#pragma unroll
        for (int c8 = 0; c8 < 16; c8++) {
            s16x8 o;
#pragma unroll
            for (int jj = 0; jj < 8; jj++) {
                int c = c8 * 8 + jj;
                float a = bb_s[c] * ws;
#pragma unroll
                for (int j = 0; j < 11; j++) a += s[j] * Wb_s[j * 128 + c];
                o[jj] = f2bf(a);
            }
            *(s16x8*)(erow + c8 * 8) = o;
        }
    } else if (blk < NSB + EAB) {
        // ---- enc_atom: h0 = x @ W_atom + b_atom -> bf16 ----
        // k-major LDS tile as[k][row], row stride 36 floats.
        float* as = shpool;  // 48*36 = 1728 floats
        int row0 = (blk - NSB) * 32;
        for (int i = t; i < 32 * 48; i += 256) {
            int r = i / 48, k = i - r * 48;
            int gr = row0 + r;
            as[k * 36 + r] = (gr < NNODES) ? X[gr * 48 + k] : 0.f;
        }
        __syncthreads();
        int c = t & 127, rh = t >> 7;
        float acc[16];
#pragma unroll
        for (int i = 0; i < 16; i++) acc[i] = 0.f;
        for (int k = 0; k < 48; k++) {
            float w = Wa[k * 128 + c];
            const float* rowv = &as[k * 36 + rh * 16];
            float4 v0 = *(const float4*)(rowv + 0);
            float4 v1 = *(const float4*)(rowv + 4);
            float4 v2 = *(const float4*)(rowv + 8);
            float4 v3 = *(const float4*)(rowv + 12);
            acc[0] += v0.x * w;  acc[1] += v0.y * w;
            acc[2] += v0.z * w;  acc[3] += v0.w * w;
            acc[4] += v1.x * w;  acc[5] += v1.y * w;
            acc[6] += v1.z * w;  acc[7] += v1.w * w;
            acc[8] += v2.x * w;  acc[9] += v2.y * w;
            acc[10] += v2.z * w; acc[11] += v2.w * w;
            acc[12] += v3.x * w; acc[13] += v3.y * w;
            acc[14] += v3.z * w; acc[15] += v3.w * w;
        }
        float bb = ba[c];
        for (int i = 0; i < 16; i++) {
            int gr = row0 + rh * 16 + i;
            if (gr < NNODES) Hhi[(size_t)gr * 128 + c] = f2bf(acc[i] + bb);
        }
    } else {
        // ---- bprep: weight fragments, hi/lo planes ----
        int idx = (blk - NSB - EAB) * 256 + t;
        if (idx >= NLAYERS * 32768) return;
        int layer = idx >> 15;
        int r = idx & 32767;
        int k = r >> 7, col = r & 127;
        float w = (k < 128) ? Wl[layer * 16384 + k * 128 + col]
                            : Wr[layer * 16384 + (k - 128) * 128 + col];
        short hi = f2bf(w);
        short lo = f2bf(w - bf2f(hi));
        int ks = k >> 4, half = (k >> 3) & 1, j = k & 7;
        int nt = col >> 5, n32 = col & 31;
        int fo = ((nt * 2 + half) * 32 + n32) * 8 + j;
        short* base = Bf + (size_t)layer * 65536 + ks * 4096;
        base[fo] = hi;
        base[2048 + fo] = lo;
    }
}

// ---------------- fused agg + GEMM v2: block = 32 nodes ----------------------
// Phase 1: one 8-lane gather chain per thread (identical TLP to standalone agg:
// 256 threads = 32 nodes x 8 lanes, 1563 blocks ~ 6/CU). Results + the node's
// own Hhi row land in LDS (row stride 140 shorts -> ~2-way banks on b128 read).
// Phase 2: 32x128 GEMM over K=256; A entirely from LDS, B (hi/lo planes) from
// L2-resident Bf, one 32-col strip per wave. Removes the Ahi HBM round-trip
// and one dispatch per layer; block-local dependency makes fusion legal.
#define AG_STRIDE 140
__global__ __launch_bounds__(256) void agg_gemm(const short* __restrict__ Hhi,
                                                const short* __restrict__ Ehi,
                                                const int* __restrict__ rowptr,
                                                const int2* __restrict__ epg,
                                                const short* __restrict__ Bf,
                                                const float* __restrict__ bias,
                                                short* __restrict__ Cbf,
                                                float* __restrict__ stat) {
    __shared__ short sA[32 * AG_STRIDE];  // agg rows (k 0..127)
    __shared__ short sH[32 * AG_STRIDE];  // own-h rows (k 128..255)
    __shared__ float s_s[128], s_q[128];
    int t = threadIdx.x;
    int row0 = blockIdx.x * 32;

    // ---- phase 1: gather ----
    {
        int lane = t & 7, slot = t >> 3;
        int c16 = lane * 16;
        int node = row0 + slot;
        s16x8 o0 = {0, 0, 0, 0, 0, 0, 0, 0}, o1 = {0, 0, 0, 0, 0, 0, 0, 0};
        s16x8 h0c = {0, 0, 0, 0, 0, 0, 0, 0}, h1c = {0, 0, 0, 0, 0, 0, 0, 0};
        if (node < NNODES) {
            int b = rowptr[node], e = rowptr[node + 1];
            float s[16];
#pragma unroll
            for (int j = 0; j < 16; j++) s[j] = 0.f;
            int p = b;
            if ((p & 1) && p < e) {  // peel to even index for int4 epg loads
                int2 pk0 = epg[p];
                float w0 = __int_as_float(pk0.y);
                s16x8 g0 = *(const s16x8*)&Hhi[(size_t)pk0.x * 128 + c16];
                s16x8 g1 = *(const s16x8*)&Hhi[(size_t)pk0.x * 128 + c16 + 8];
#pragma unroll
                for (int j = 0; j < 8; j++) {
                    s[j] += bf2f(g0[j]) * w0;
                    s[8 + j] += bf2f(g1[j]) * w0;
                }
                p++;
            }
            for (; p + 1 < e; p += 2) {
                int4 ee = *(const int4*)&epg[p];  // {src0,w0,src1,w1}
                float w0 = __int_as_float(ee.y), w1 = __int_as_float(ee.w);
                s16x8 a0 = *(const s16x8*)&Hhi[(size_t)ee.x * 128 + c16];
                s16x8 a1 = *(const s16x8*)&Hhi[(size_t)ee.x * 128 + c16 + 8];
                s16x8 b0 = *(const s16x8*)&Hhi[(size_t)ee.z * 128 + c16];
                s16x8 b1 = *(const s16x8*)&Hhi[(size_t)ee.z * 128 + c16 + 8];
#pragma unroll
                for (int j = 0; j < 8; j++) {
                    s[j] += bf2f(a0[j]) * w0 + bf2f(b0[j]) * w1;
                    s[8 + j] += bf2f(a1[j]) * w0 + bf2f(b1[j]) * w1;
                }
            }
            if (p < e) {
                int2 pk0 = epg[p];
                float w0 = __int_as_float(pk0.y);
                s16x8 g0 = *(const s16x8*)&Hhi[(size_t)pk0.x * 128 + c16];
                s16x8 g1 = *(const s16x8*)&Hhi[(size_t)pk0.x * 128 + c16 + 8];
#pragma unroll
                for (int j = 0; j < 8; j++) {
                    s[j] += bf2f(g0[j]) * w0;
                    s[8 + j] += bf2f(g1[j]) * w0;
                }
            }
            float inv = 1.f / fmaxf((float)(e - b), 1.f);
            s16x8 ea0 = *(const s16x8*)&Ehi[(size_t)node * 128 + c16];
            s16x8 ea1 = *(const s16x8*)&Ehi[(size_t)node * 128 + c16 + 8];
            h0c = *(const s16x8*)&Hhi[(size_t)node * 128 + c16];
            h1c = *(const s16x8*)&Hhi[(size_t)node * 128 + c16 + 8];
#pragma unroll
            for (int j = 0; j < 8; j++) {
                o0[j] = f2bf((s[j] + bf2f(ea0[j])) * inv);
                o1[j] = f2bf((s[8 + j] + bf2f(ea1[j])) * inv);
            }
        }
        short* ar = sA + slot * AG_STRIDE + c16;
        short* hr = sH + slot * AG_STRIDE + c16;
        *(s16x8*)ar = o0;
        *(s16x8*)(ar + 8) = o1;
        *(s16x8*)hr = h0c;
        *(s16x8*)(hr + 8) = h1c;
    }
    __syncthreads();

    // ---- phase 2: GEMM, wave = 32 rows x 32 cols, K=256 ----
    int wave = t >> 6, lane = t & 63;
    int n32 = lane & 31, half = lane >> 5;
    int acol = half * 8;
    const short* sArow = sA + n32 * AG_STRIDE + acol;
    const short* sHrow = sH + n32 * AG_STRIDE + acol;
    const short* bb0 = Bf + wave * 512 + half * 256 + n32 * 8;

    f32x16 acc = (f32x16)(0.f);

    s16x8 ahA, ahB, bhA, blA, bhB, blB;
    ahA = *(const s16x8*)(sArow);
    ahB = *(const s16x8*)(sArow + 16);
    bhA = *(const s16x8*)(bb0);
    blA = *(const s16x8*)(bb0 + 2048);
    bhB = *(const s16x8*)(bb0 + 4096);
    blB = *(const s16x8*)(bb0 + 4096 + 2048);

#pragma unroll
    for (int ks = 0; ks < 16; ks++) {
        s16x8 ahC = {0, 0, 0, 0, 0, 0, 0, 0}, bhC, blC;
        if (ks < 14) {
            int kn = ks + 2;
            const short* arow = (kn < 8) ? (sArow + kn * 16) : (sHrow + (kn - 8) * 16);
            ahC = *(const s16x8*)arow;
            const short* bbn = bb0 + kn * 4096;
            bhC = *(const s16x8*)(bbn);
            blC = *(const s16x8*)(bbn + 2048);
        }
        acc = __builtin_amdgcn_mfma_f32_32x32x16_bf16(ahA, bhA, acc, 0, 0, 0);
        acc = __builtin_amdgcn_mfma_f32_32x32x16_bf16(ahA, blA, acc, 0, 0, 0);
        ahA = ahB; ahB = ahC;
        bhA = bhB; bhB = bhC;
        blA = blB; blB = blC;
    }

    // epilogue: bias, bf16 C write, fused BN partial stats
    int col = wave * 32 + n32;
    float bb = bias[col];
    float ss = 0.f, qq = 0.f;
#pragma unroll
    for (int reg = 0; reg < 16; reg++) {
        int r = row0 + (reg & 3) + 8 * (reg >> 2) + 4 * half;
        if (r < NNODES) {
            float v = acc[reg] + bb;
            Cbf[(size_t)r * 128 + col] = f2bf(v);
            ss += v;
            qq += v * v;
        }
    }
    ss += __shfl_xor(ss, 32);
    qq += __shfl_xor(qq, 32);
    if (half == 0) {  // per-wave disjoint 32-col strips: plain stores
        s_s[col] = ss;
        s_q[col] = qq;
    }
    __syncthreads();
    if (t < 128) {
        atomicAdd(&stat[t], s_s[t]);
        atomicAdd(&stat[128 + t], s_q[t]);
    }
}

// ---------------- BN apply (+inline coef) + ReLU + xpool ---------------------
__global__ __launch_bounds__(256) void bn_apply(const short* __restrict__ Cbf,
                                                short* __restrict__ Hhi,
                                                float* __restrict__ Hf32,
                                                const float* __restrict__ stat,
                                                const float* __restrict__ gamma,
                                                const float* __restrict__ beta,
                                                const int* __restrict__ batch,
                                                float* __restrict__ pool,
                                                int layer, int relu) {
    __shared__ float csc[128], csh[128];
    int t = threadIdx.x;
    if (t < 128) {
        const float invM = 1.f / (float)NNODES;
        float mu = stat[t] * invM;
        float var = stat[128 + t] * invM - mu * mu;
        float inv = rsqrtf(var + BN_EPS);
        float sc = gamma[t] * inv;
        csc[t] = sc;
        csh[t] = beta[t] - mu * sc;
    }
    __syncthreads();
    int lane = t & 31, grp = t >> 5;
    int c4 = lane * 4;
    float4 sc = *(const float4*)&csc[c4];
    float4 sh = *(const float4*)&csh[c4];
    int row0 = blockIdx.x * 256;
    float4 accp = {0.f, 0.f, 0.f, 0.f};
    int curg = -1;
    float* pbase = pool + layer * 128 + c4;
    for (int rr = grp; rr < 256; rr += 8) {
        int r = row0 + rr;
        if (r >= NNODES) break;
        ushort4 cv = *(const ushort4*)&Cbf[(size_t)r * 128 + c4];
        float4 v;
        v.x = bf2f((short)cv.x) * sc.x + sh.x;
        v.y = bf2f((short)cv.y) * sc.y + sh.y;
        v.z = bf2f((short)cv.z) * sc.z + sh.z;
        v.w = bf2f((short)cv.w) * sc.w + sh.w;
        if (relu) {
            v.x = fmaxf(v.x, 0.f);
            v.y = fmaxf(v.y, 0.f);
            v.z = fmaxf(v.z, 0.f);
            v.w = fmaxf(v.w, 0.f);
        }
        if (Hf32) {
            *(float4*)&Hf32[(size_t)r * 128 + c4] = v;
        } else {
            ushort4 hv;
            hv.x = (unsigned short)f2bf(v.x);
            hv.y = (unsigned short)f2bf(v.y);
            hv.z = (unsigned short)f2bf(v.z);
            hv.w = (unsigned short)f2bf(v.w);
            *(ushort4*)&Hhi[(size_t)r * 128 + c4] = hv;
        }
        int g = batch[r];
        if (g != curg) {
            if (curg >= 0) {
                float* p = pbase + curg * 640;
                atomicAdd(p + 0, accp.x);
                atomicAdd(p + 1, accp.y);
                atomicAdd(p + 2, accp.z);
                atomicAdd(p + 3, accp.w);
            }
            curg = g;
            accp.x = accp.y = accp.z = accp.w = 0.f;
        }
        accp.x += v.x;
        accp.y += v.y;
        accp.z += v.z;
        accp.w += v.w;
    }
    if (curg >= 0) {
        float* p = pbase + curg * 640;
        atomicAdd(p + 0, accp.x);
        atomicAdd(p + 1, accp.y);
        atomicAdd(p + 2, accp.z);
        atomicAdd(p + 3, accp.w);
    }
}

extern "C" void kernel_launch(void* const* d_in, const int* in_sizes, int n_in,
                              void* d_out, int out_size, void* d_ws, size_t ws_size,
                              hipStream_t stream) {
    const int* batch = (const int*)d_in[0];
    const float* x = (const float*)d_in[1];
    const int* edge_index = (const int*)d_in[2];
    const float* edge_attr = (const float*)d_in[3];
    const float* edge_weight = (const float*)d_in[4];
    const float* W_atom = (const float*)d_in[5];
    const float* b_atom = (const float*)d_in[6];
    const float* W_bond = (const float*)d_in[7];
    const float* b_bond = (const float*)d_in[8];
    const float* Wl = (const float*)d_in[9];
    const float* bl = (const float*)d_in[10];
    const float* Wr = (const float*)d_in[11];
    const float* gamma = (const float*)d_in[12];
    const float* beta = (const float*)d_in[13];
    float* out = (float*)d_out;

    // ---- workspace layout ----
    char* ws = (char*)d_ws;
    size_t off = 0;
    auto alloc = [&](size_t bytes) -> void* {
        void* p = ws + off;
        off += (bytes + 255) & ~(size_t)255;
        return p;
    };
    short* Hhi = (short*)alloc((size_t)NNODES * 128 * 2);
    short* Cbf = (short*)alloc((size_t)NNODES * 128 * 2);
    short* Ehi = (short*)alloc((size_t)NNODES * 128 * 2);
    int* epk = (int*)alloc((size_t)NEDGES * 32);
    int2* epg = (int2*)alloc((size_t)NEDGES * 8);
    int* rowptr = (int*)alloc((size_t)(NNODES + 1) * 4);
    int* cursor = (int*)alloc((size_t)NNODES * 4);
    int* deg = (int*)alloc((size_t)NNODES * 4);
    float* stat = (float*)alloc(NLAYERS * 256 * 4);
    int* local_excl = (int*)alloc((size_t)NNODES * 4);
    int* part = (int*)alloc(SCAN_BLOCKS * 4);
    int* blockoff = (int*)alloc(SCAN_BLOCKS * 4);
    short* Bf = (short*)alloc((size_t)NLAYERS * 65536 * 2);

    // ---- preprocessing ----
    init_kernel<<<(NGRAPHS * 640 + 255) / 256, 256, 0, stream>>>(out, deg, stat);
    deg_kernel<<<(NEDGES + 255) / 256, 256, 0, stream>>>(edge_index, deg);
    scan1<<<SCAN_BLOCKS, 256, 0, stream>>>(deg, local_excl, part);
    scan2<<<1, 256, 0, stream>>>(part, blockoff, rowptr);
    scan3<<<SCAN_BLOCKS, 256, 0, stream>>>(local_excl, blockoff, rowptr, cursor);
    edge_fill<<<(NEDGES + 255) / 256, 256, 0, stream>>>(edge_index, edge_weight,
                                                        edge_attr, cursor, epk);
    prep2<<<NSB + EAB + BPB, 256, 0, stream>>>(rowptr, epk, epg, W_bond, b_bond, Ehi,
                                               x, W_atom, b_atom, Hhi, Wl, Wr, Bf);

    // ---- layers ----
    for (int i = 0; i < NLAYERS; i++) {
        agg_gemm<<<(NNODES + 31) / 32, 256, 0, stream>>>(Hhi, Ehi, rowptr, epg,
                                                         Bf + (size_t)i * 65536,
                                                         bl + i * 128, Cbf,
                                                         stat + i * 256);
        int last = (i == NLAYERS - 1);
        bn_apply<<<(NNODES + 255) / 256, 256, 0, stream>>>(
            Cbf, Hhi, last ? (out + (size_t)NGRAPHS * 640) : nullptr,
            stat + i * 256, gamma + i * 128, beta + i * 128, batch, out, i,
            last ? 0 : 1);
    }
}

// Round 5
// 540.303 us; speedup vs baseline: 1.2414x; 1.2414x over previous
//
#include <hip/hip_runtime.h>
#include <hip/hip_bf16.h>

#define NNODES 50000
#define NEDGES 600000
#define NGRAPHS 128
#define EMB 128
#define NLAYERS 5
#define BN_EPS 1e-5f
#define SCAN_BLOCKS ((NNODES + 255) / 256)    // 196
#define NSB ((NNODES + 255) / 256)            // 196 node_S_bond blocks
#define EAB ((NNODES + 31) / 32)              // 1563 enc_atom blocks
#define BPB ((NLAYERS * 32768 + 255) / 256)   // 640 bprep blocks

typedef short s16x8 __attribute__((ext_vector_type(8)));
typedef float f32x16 __attribute__((ext_vector_type(16)));

__device__ __forceinline__ short f2bf(float f) {
    unsigned u = __builtin_bit_cast(unsigned, f);
    unsigned r = (u + 0x7fffu + ((u >> 16) & 1u)) >> 16;  // RNE
    return (short)r;
}
__device__ __forceinline__ float bf2f(short s) {
    return __builtin_bit_cast(float, ((unsigned)(unsigned short)s) << 16);
}

// ---------------- init: zero pool region, deg, stat (replaces 3 memsets) -----
__global__ __launch_bounds__(256) void init_kernel(float* __restrict__ pool,
                                                   int* __restrict__ deg,
                                                   float* __restrict__ stat) {
    int i = blockIdx.x * 256 + threadIdx.x;
    if (i < NGRAPHS * 640) pool[i] = 0.f;
    if (i < NNODES) deg[i] = 0;
    if (i < NLAYERS * 256) stat[i] = 0.f;
}

// ---------------- deg histogram (int atomics only) ---------------------------
__global__ __launch_bounds__(256) void deg_kernel(const int* __restrict__ ei,
                                                  int* __restrict__ deg) {
    int e = blockIdx.x * 256 + threadIdx.x;
    if (e >= NEDGES) return;
    atomicAdd(&deg[ei[NEDGES + e]], 1);
}

// ---------------- scan, 2 dispatches ----------------------------------------
__global__ __launch_bounds__(256) void scan1(const int* __restrict__ deg,
                                             int* __restrict__ local_excl,
                                             int* __restrict__ part) {
    __shared__ int sh[256];
    int t = threadIdx.x;
    int i = blockIdx.x * 256 + t;
    int v = (i < NNODES) ? deg[i] : 0;
    sh[t] = v;
    __syncthreads();
    for (int off = 1; off < 256; off <<= 1) {
        int u = (t >= off) ? sh[t - off] : 0;
        __syncthreads();
        sh[t] += u;
        __syncthreads();
    }
    if (i < NNODES) local_excl[i] = sh[t] - v;
    if (t == 255) part[blockIdx.x] = sh[255];
}

// merged scan2+scan3: every block redundantly scans the 196 partials in LDS,
// takes its own offset, applies. Saves one dispatch (+its ~12us gap).
__global__ __launch_bounds__(256) void scan23(const int* __restrict__ part,
                                              const int* __restrict__ local_excl,
                                              int* __restrict__ rowptr,
                                              int* __restrict__ cursor) {
    __shared__ int sh[256];
    int t = threadIdx.x;
    int v = (t < SCAN_BLOCKS) ? part[t] : 0;
    sh[t] = v;
    __syncthreads();
    for (int off = 1; off < 256; off <<= 1) {
        int u = (t >= off) ? sh[t - off] : 0;
        __syncthreads();
        sh[t] += u;
        __syncthreads();
    }
    int bo = (blockIdx.x == 0) ? 0 : sh[blockIdx.x - 1];
    int i = blockIdx.x * 256 + t;
    if (i < NNODES) {
        int r = local_excl[i] + bo;
        rowptr[i] = r;
        cursor[i] = r;
    }
    if (blockIdx.x == 0 && t == 0) rowptr[NNODES] = sh[SCAN_BLOCKS - 1];
}

// ---------------- fill CSR: 32B record {src, w, 11x bf16 attr, pad} ----------
__global__ __launch_bounds__(256) void edge_fill(const int* __restrict__ ei,
                                                 const float* __restrict__ ew,
                                                 const float* __restrict__ eattr,
                                                 int* __restrict__ cursor,
                                                 int* __restrict__ epk) {
    int e = blockIdx.x * 256 + threadIdx.x;
    if (e >= NEDGES) return;
    int src = ei[e];
    int dst = ei[NEDGES + e];
    int pos = atomicAdd(&cursor[dst], 1);
    int pk[8];
    pk[0] = src;
    pk[1] = __float_as_int(ew[e]);
    unsigned short a[12];
#pragma unroll
    for (int j = 0; j < 11; j++) a[j] = (unsigned short)f2bf(eattr[e * 11 + j]);
    a[11] = 0;
#pragma unroll
    for (int j = 0; j < 6; j++)
        pk[2 + j] = (int)a[2 * j] | ((int)a[2 * j + 1] << 16);
    int* dstp = epk + (size_t)pos * 8;
    *(int4*)dstp = *(int4*)pk;
    *(int4*)(dstp + 4) = *(int4*)(pk + 4);
}

// ---------------- prep2: heterogeneous {node_S+enc_bond | enc_atom | bprep} --
__global__ __launch_bounds__(256) void prep2(const int* __restrict__ rowptr,
                                             const int* __restrict__ epk,
                                             int2* __restrict__ epg,
                                             const float* __restrict__ Wb,
                                             const float* __restrict__ bbond,
                                             short* __restrict__ Ehi,
                                             const float* __restrict__ X,
                                             const float* __restrict__ Wa,
                                             const float* __restrict__ ba,
                                             short* __restrict__ Hhi,
                                             const float* __restrict__ Wl,
                                             const float* __restrict__ Wr,
                                             short* __restrict__ Bf) {
    __shared__ float shpool[1792];  // 7168 B, aliased by branches
    int blk = blockIdx.x;
    int t = threadIdx.x;

    if (blk < NSB) {
        // ---- node_S + enc_bond fused: thread-per-node ----
        float* Wb_s = shpool;        // 11*128 = 1408
        float* bb_s = shpool + 1408; // 128
        for (int i = t; i < 1408; i += 256) Wb_s[i] = Wb[i];
        if (t < 128) bb_s[t] = bbond[t];
        __syncthreads();
        int node = blk * 256 + t;
        if (node >= NNODES) return;
        int b = rowptr[node], e = rowptr[node + 1];
        float s[11];
#pragma unroll
        for (int j = 0; j < 11; j++) s[j] = 0.f;
        float ws = 0.f;
        for (int p = b; p < e; p++) {
            const int* pk = epk + (size_t)p * 8;
            int4 lo = *(const int4*)pk;
            int4 hi = *(const int4*)(pk + 4);
            float w = __int_as_float(lo.y);
            ws += w;
            epg[p] = make_int2(lo.x, lo.y);   // compact {src,w} gather record
            int packed[6] = {lo.z, lo.w, hi.x, hi.y, hi.z, hi.w};
#pragma unroll
            for (int j = 0; j < 11; j++) {
                short v = (short)((packed[j >> 1] >> ((j & 1) * 16)) & 0xffff);
                s[j] += bf2f(v) * w;
            }
        }
        short* erow = Ehi + (size_t)node * 128;
#pragma unroll
        for (int c8 = 0; c8 < 16; c8++) {
            s16x8 o;
#pragma unroll
            for (int jj = 0; jj < 8; jj++) {
                int c = c8 * 8 + jj;
                float a = bb_s[c] * ws;
#pragma unroll
                for (int j = 0; j < 11; j++) a += s[j] * Wb_s[j * 128 + c];
                o[jj] = f2bf(a);
            }
            *(s16x8*)(erow + c8 * 8) = o;
        }
    } else if (blk < NSB + EAB) {
        // ---- enc_atom: h0 = x @ W_atom + b_atom -> bf16 ----
        float* as = shpool;  // 48*36 = 1728 floats, k-major, stride 36
        int row0 = (blk - NSB) * 32;
        for (int i = t; i < 32 * 48; i += 256) {
            int r = i / 48, k = i - r * 48;
            int gr = row0 + r;
            as[k * 36 + r] = (gr < NNODES) ? X[gr * 48 + k] : 0.f;
        }
        __syncthreads();
        int c = t & 127, rh = t >> 7;
        float acc[16];
#pragma unroll
        for (int i = 0; i < 16; i++) acc[i] = 0.f;
        for (int k = 0; k < 48; k++) {
            float w = Wa[k * 128 + c];
            const float* rowv = &as[k * 36 + rh * 16];
            float4 v0 = *(const float4*)(rowv + 0);
            float4 v1 = *(const float4*)(rowv + 4);
            float4 v2 = *(const float4*)(rowv + 8);
            float4 v3 = *(const float4*)(rowv + 12);
            acc[0] += v0.x * w;  acc[1] += v0.y * w;
            acc[2] += v0.z * w;  acc[3] += v0.w * w;
            acc[4] += v1.x * w;  acc[5] += v1.y * w;
            acc[6] += v1.z * w;  acc[7] += v1.w * w;
            acc[8] += v2.x * w;  acc[9] += v2.y * w;
            acc[10] += v2.z * w; acc[11] += v2.w * w;
            acc[12] += v3.x * w; acc[13] += v3.y * w;
            acc[14] += v3.z * w; acc[15] += v3.w * w;
        }
        float bb = ba[c];
        for (int i = 0; i < 16; i++) {
            int gr = row0 + rh * 16 + i;
            if (gr < NNODES) Hhi[(size_t)gr * 128 + c] = f2bf(acc[i] + bb);
        }
    } else {
        // ---- bprep: weight fragments, hi/lo planes ----
        int idx = (blk - NSB - EAB) * 256 + t;
        if (idx >= NLAYERS * 32768) return;
        int layer = idx >> 15;
        int r = idx & 32767;
        int k = r >> 7, col = r & 127;
        float w = (k < 128) ? Wl[layer * 16384 + k * 128 + col]
                            : Wr[layer * 16384 + (k - 128) * 128 + col];
        short hi = f2bf(w);
        short lo = f2bf(w - bf2f(hi));
        int ks = k >> 4, half = (k >> 3) & 1, j = k & 7;
        int nt = col >> 5, n32 = col & 31;
        int fo = ((nt * 2 + half) * 32 + n32) * 8 + j;
        short* base = Bf + (size_t)layer * 65536 + ks * 4096;
        base[fo] = hi;
        base[2048 + fo] = lo;
    }
}

// ---------------- aggregation with inline BN+ReLU of the source -------------
// h'(src) = max(sc*c + sh, 0) computed on the fly from prev layer's raw C
// (stat==null -> identity, no relu: layer 0 reads raw h0). 16 lanes/node,
// s16x8 gather, 4-edge unroll. Replaces the separate bn_apply dispatch.
__global__ __launch_bounds__(256) void agg_kernel(const short* __restrict__ Hsrc,
                                                  const short* __restrict__ Ehi,
                                                  const int* __restrict__ rowptr,
                                                  const int2* __restrict__ epg,
                                                  const float* __restrict__ stat,
                                                  const float* __restrict__ gamma,
                                                  const float* __restrict__ beta,
                                                  short* __restrict__ Ahi) {
    __shared__ float cscs[128], cshs[128];
    int t = threadIdx.x;
    if (t < 128) {
        float sc = 1.f, sh = 0.f;
        if (stat) {
            const float invM = 1.f / (float)NNODES;
            float mu = stat[t] * invM;
            float var = stat[128 + t] * invM - mu * mu;
            sc = gamma[t] * rsqrtf(var + BN_EPS);
            sh = beta[t] - mu * sc;
        }
        cscs[t] = sc;
        cshs[t] = sh;
    }
    __syncthreads();
    int lane = t & 15, grp = t >> 4;
    int c8 = lane * 8;
    int node = blockIdx.x * 16 + grp;
    if (node >= NNODES) return;
    float rlo = stat ? 0.f : -3.4e38f;
    float sc[8], sh[8];
#pragma unroll
    for (int j = 0; j < 8; j++) { sc[j] = cscs[c8 + j]; sh[j] = cshs[c8 + j]; }
    int b = rowptr[node], e = rowptr[node + 1];
    float s[8];
#pragma unroll
    for (int j = 0; j < 8; j++) s[j] = 0.f;
    int p = b;
    for (; p + 3 < e; p += 4) {
        int2 e0 = epg[p], e1 = epg[p + 1], e2 = epg[p + 2], e3 = epg[p + 3];
        float w0 = __int_as_float(e0.y), w1 = __int_as_float(e1.y);
        float w2 = __int_as_float(e2.y), w3 = __int_as_float(e3.y);
        s16x8 h0 = *(const s16x8*)&Hsrc[(size_t)e0.x * 128 + c8];
        s16x8 h1 = *(const s16x8*)&Hsrc[(size_t)e1.x * 128 + c8];
        s16x8 h2 = *(const s16x8*)&Hsrc[(size_t)e2.x * 128 + c8];
        s16x8 h3 = *(const s16x8*)&Hsrc[(size_t)e3.x * 128 + c8];
#pragma unroll
        for (int j = 0; j < 8; j++) {
            float v0 = fmaxf(bf2f(h0[j]) * sc[j] + sh[j], rlo);
            float v1 = fmaxf(bf2f(h1[j]) * sc[j] + sh[j], rlo);
            float v2 = fmaxf(bf2f(h2[j]) * sc[j] + sh[j], rlo);
            float v3 = fmaxf(bf2f(h3[j]) * sc[j] + sh[j], rlo);
            s[j] += v0 * w0 + v1 * w1 + v2 * w2 + v3 * w3;
        }
    }
    for (; p < e; p++) {
        int2 pk0 = epg[p];
        float w0 = __int_as_float(pk0.y);
        s16x8 h0 = *(const s16x8*)&Hsrc[(size_t)pk0.x * 128 + c8];
#pragma unroll
        for (int j = 0; j < 8; j++)
            s[j] += fmaxf(bf2f(h0[j]) * sc[j] + sh[j], rlo) * w0;
    }
    float inv = 1.f / fmaxf((float)(e - b), 1.f);
    s16x8 ea = *(const s16x8*)&Ehi[(size_t)node * 128 + c8];
    s16x8 o;
#pragma unroll
    for (int j = 0; j < 8; j++) o[j] = f2bf((s[j] + bf2f(ea[j])) * inv);
    *(s16x8*)&Ahi[(size_t)node * 128 + c8] = o;
}

// ---------------- MFMA GEMM with inline BN+ReLU on the h@Wr half -------------
// A k=0..127 from Ahi; k=128..255 built from raw prev-layer C via the same
// affine (bit-identical to the old bn_apply->Hhi->gemm path).
__global__ __launch_bounds__(256) void layer_gemm(const short* __restrict__ Ahi,
                                                  const short* __restrict__ Hsrc,
                                                  const float* __restrict__ statp,
                                                  const float* __restrict__ gamma,
                                                  const float* __restrict__ beta,
                                                  const short* __restrict__ Bf,
                                                  const float* __restrict__ bias,
                                                  short* __restrict__ Cbf,
                                                  float* __restrict__ stat) {
    __shared__ float s_s[128], s_q[128];
    __shared__ float csc[128], csh[128];
    int t = threadIdx.x;
    int wave = t >> 6, lane = t & 63;
    int n32 = lane & 31, half = lane >> 5;
    int row0 = blockIdx.x * 128 + wave * 32;

    if (t < 128) {
        s_s[t] = 0.f;
        s_q[t] = 0.f;
        float sc = 1.f, sh = 0.f;
        if (statp) {
            const float invM = 1.f / (float)NNODES;
            float mu = statp[t] * invM;
            float var = statp[128 + t] * invM - mu * mu;
            sc = gamma[t] * rsqrtf(var + BN_EPS);
            sh = beta[t] - mu * sc;
        }
        csc[t] = sc;
        csh[t] = sh;
    }
    __syncthreads();
    float rlo = statp ? 0.f : -3.4e38f;

    int myrow = row0 + n32;
    bool rowok = myrow < NNODES;
    size_t rbase = (size_t)myrow * 128;
    int acol = half * 8;

    f32x16 acc[4];
#pragma unroll
    for (int i = 0; i < 4; i++) acc[i] = (f32x16)(0.f);

    const short* bb0 = Bf + half * 256 + n32 * 8;

    s16x8 ahA = {0, 0, 0, 0, 0, 0, 0, 0}, ahB = {0, 0, 0, 0, 0, 0, 0, 0};
    s16x8 bhA[4], blA[4], bhB[4], blB[4];
    // prologue: ks 0 -> A, ks 1 -> B (both from Ahi half)
    if (rowok) {
        ahA = *(const s16x8*)(Ahi + rbase + acol);
        ahB = *(const s16x8*)(Ahi + rbase + 16 + acol);
    }
#pragma unroll
    for (int nt = 0; nt < 4; nt++) {
        bhA[nt] = *(const s16x8*)(bb0 + nt * 512);
        blA[nt] = *(const s16x8*)(bb0 + 2048 + nt * 512);
        bhB[nt] = *(const s16x8*)(bb0 + 4096 + nt * 512);
        blB[nt] = *(const s16x8*)(bb0 + 4096 + 2048 + nt * 512);
    }

#pragma unroll
    for (int ks = 0; ks < 16; ks++) {
        s16x8 ahC = {0, 0, 0, 0, 0, 0, 0, 0};
        s16x8 bhC[4], blC[4];
        if (ks < 14) {
            int kn = ks + 2;
            if (rowok) {
                if (kn < 8) {
                    ahC = *(const s16x8*)(Ahi + rbase + kn * 16 + acol);
                } else {
                    s16x8 hv = *(const s16x8*)(Hsrc + rbase + (kn & 7) * 16 + acol);
                    int kc = (kn & 7) * 16 + acol;
                    float4 scA = *(const float4*)&csc[kc];
                    float4 scB = *(const float4*)&csc[kc + 4];
                    float4 shA = *(const float4*)&csh[kc];
                    float4 shB = *(const float4*)&csh[kc + 4];
                    ahC[0] = f2bf(fmaxf(bf2f(hv[0]) * scA.x + shA.x, rlo));
                    ahC[1] = f2bf(fmaxf(bf2f(hv[1]) * scA.y + shA.y, rlo));
                    ahC[2] = f2bf(fmaxf(bf2f(hv[2]) * scA.z + shA.z, rlo));
                    ahC[3] = f2bf(fmaxf(bf2f(hv[3]) * scA.w + shA.w, rlo));
                    ahC[4] = f2bf(fmaxf(bf2f(hv[4]) * scB.x + shB.x, rlo));
                    ahC[5] = f2bf(fmaxf(bf2f(hv[5]) * scB.y + shB.y, rlo));
                    ahC[6] = f2bf(fmaxf(bf2f(hv[6]) * scB.z + shB.z, rlo));
                    ahC[7] = f2bf(fmaxf(bf2f(hv[7]) * scB.w + shB.w, rlo));
                }
            }
            const short* bbn = bb0 + kn * 4096;
#pragma unroll
            for (int nt = 0; nt < 4; nt++) {
                bhC[nt] = *(const s16x8*)(bbn + nt * 512);
                blC[nt] = *(const s16x8*)(bbn + 2048 + nt * 512);
            }
        }
#pragma unroll
        for (int nt = 0; nt < 4; nt++) {
            acc[nt] = __builtin_amdgcn_mfma_f32_32x32x16_bf16(ahA, bhA[nt], acc[nt], 0, 0, 0);
            acc[nt] = __builtin_amdgcn_mfma_f32_32x32x16_bf16(ahA, blA[nt], acc[nt], 0, 0, 0);
        }
        ahA = ahB;
        ahB = ahC;
#pragma unroll
        for (int nt = 0; nt < 4; nt++) {
            bhA[nt] = bhB[nt];
            blA[nt] = blB[nt];
            bhB[nt] = bhC[nt];
            blB[nt] = blC[nt];
        }
    }

    // epilogue: bias, bf16 C write, fused BN partial stats
#pragma unroll
    for (int nt = 0; nt < 4; nt++) {
        int col = nt * 32 + n32;
        float bb = bias[col];
        float ss = 0.f, qq = 0.f;
#pragma unroll
        for (int reg = 0; reg < 16; reg++) {
            int r = row0 + (reg & 3) + 8 * (reg >> 2) + 4 * half;
            if (r < NNODES) {
                float v = acc[nt][reg] + bb;
                Cbf[(size_t)r * 128 + col] = f2bf(v);
                ss += v;
                qq += v * v;
            }
        }
        ss += __shfl_xor(ss, 32);
        qq += __shfl_xor(qq, 32);
        if (half == 0) {
            atomicAdd(&s_s[col], ss);
            atomicAdd(&s_q[col], qq);
        }
    }
    __syncthreads();
    if (t < 128) {
        atomicAdd(&stat[t], s_s[t]);
        atomicAdd(&stat[128 + t], s_q[t]);
    }
}

// ---------------- pool5: all 5 layers' BN+ReLU+xpool + final Hf32 ------------
// Replaces 5 bn_apply dispatches with one. Reads Cbf[l] (raw C, bf16) and
// applies each layer's affine; relu for l<4; writes Hf32 for l==4.
__global__ __launch_bounds__(256) void pool5(const short* __restrict__ Cbf,
                                             const float* __restrict__ stat,
                                             const float* __restrict__ gamma,
                                             const float* __restrict__ beta,
                                             const int* __restrict__ batch,
                                             float* __restrict__ pool,
                                             float* __restrict__ Hf32) {
    __shared__ float csc[NLAYERS * 128], csh[NLAYERS * 128];
    int t = threadIdx.x;
    for (int i = t; i < NLAYERS * 128; i += 256) {
        int l = i >> 7, c = i & 127;
        const float invM = 1.f / (float)NNODES;
        float mu = stat[l * 256 + c] * invM;
        float var = stat[l * 256 + 128 + c] * invM - mu * mu;
        float sc = gamma[i] * rsqrtf(var + BN_EPS);
        csc[i] = sc;
        csh[i] = beta[i] - mu * sc;
    }
    __syncthreads();
    int lane = t & 31, grp = t >> 5;
    int c4 = lane * 4;
    float4 sc[NLAYERS], sh[NLAYERS];
#pragma unroll
    for (int l = 0; l < NLAYERS; l++) {
        sc[l] = *(const float4*)&csc[l * 128 + c4];
        sh[l] = *(const float4*)&csh[l * 128 + c4];
    }
    int row0 = blockIdx.x * 256;
    float4 accp[NLAYERS];
#pragma unroll
    for (int l = 0; l < NLAYERS; l++) accp[l] = make_float4(0.f, 0.f, 0.f, 0.f);
    int curg = -1;
    float* pbase = pool + c4;
    for (int rr = grp; rr < 256; rr += 8) {
        int r = row0 + rr;
        if (r >= NNODES) break;
        int g = batch[r];
        if (g != curg) {
            if (curg >= 0) {
#pragma unroll
                for (int l = 0; l < NLAYERS; l++) {
                    float* p = pbase + curg * 640 + l * 128;
                    atomicAdd(p + 0, accp[l].x);
                    atomicAdd(p + 1, accp[l].y);
                    atomicAdd(p + 2, accp[l].z);
                    atomicAdd(p + 3, accp[l].w);
                }
            }
            curg = g;
#pragma unroll
            for (int l = 0; l < NLAYERS; l++) accp[l] = make_float4(0.f, 0.f, 0.f, 0.f);
        }
#pragma unroll
        for (int l = 0; l < NLAYERS; l++) {
            ushort4 cv = *(const ushort4*)&Cbf[(size_t)l * NNODES * 128 +
                                              (size_t)r * 128 + c4];
            float4 v;
            v.x = bf2f((short)cv.x) * sc[l].x + sh[l].x;
            v.y = bf2f((short)cv.y) * sc[l].y + sh[l].y;
            v.z = bf2f((short)cv.z) * sc[l].z + sh[l].z;
            v.w = bf2f((short)cv.w) * sc[l].w + sh[l].w;
            if (l < NLAYERS - 1) {
                v.x = fmaxf(v.x, 0.f);
                v.y = fmaxf(v.y, 0.f);
                v.z = fmaxf(v.z, 0.f);
                v.w = fmaxf(v.w, 0.f);
            } else {
                *(float4*)&Hf32[(size_t)r * 128 + c4] = v;
            }
            accp[l].x += v.x;
            accp[l].y += v.y;
            accp[l].z += v.z;
            accp[l].w += v.w;
        }
    }
    if (curg >= 0) {
#pragma unroll
        for (int l = 0; l < NLAYERS; l++) {
            float* p = pbase + curg * 640 + l * 128;
            atomicAdd(p + 0, accp[l].x);
            atomicAdd(p + 1, accp[l].y);
            atomicAdd(p + 2, accp[l].z);
            atomicAdd(p + 3, accp[l].w);
        }
    }
}

extern "C" void kernel_launch(void* const* d_in, const int* in_sizes, int n_in,
                              void* d_out, int out_size, void* d_ws, size_t ws_size,
                              hipStream_t stream) {
    const int* batch = (const int*)d_in[0];
    const float* x = (const float*)d_in[1];
    const int* edge_index = (const int*)d_in[2];
    const float* edge_attr = (const float*)d_in[3];
    const float* edge_weight = (const float*)d_in[4];
    const float* W_atom = (const float*)d_in[5];
    const float* b_atom = (const float*)d_in[6];
    const float* W_bond = (const float*)d_in[7];
    const float* b_bond = (const float*)d_in[8];
    const float* Wl = (const float*)d_in[9];
    const float* bl = (const float*)d_in[10];
    const float* Wr = (const float*)d_in[11];
    const float* gamma = (const float*)d_in[12];
    const float* beta = (const float*)d_in[13];
    float* out = (float*)d_out;

    // ---- workspace layout ----
    char* ws = (char*)d_ws;
    size_t off = 0;
    auto alloc = [&](size_t bytes) -> void* {
        void* p = ws + off;
        off += (bytes + 255) & ~(size_t)255;
        return p;
    };
    short* Hhi = (short*)alloc((size_t)NNODES * 128 * 2);
    short* Ahi = (short*)alloc((size_t)NNODES * 128 * 2);
    short* Ehi = (short*)alloc((size_t)NNODES * 128 * 2);
    short* Cbf = (short*)alloc((size_t)NLAYERS * NNODES * 128 * 2);  // 5 layers
    int* epk = (int*)alloc((size_t)NEDGES * 32);
    int2* epg = (int2*)alloc((size_t)NEDGES * 8);
    int* rowptr = (int*)alloc((size_t)(NNODES + 1) * 4);
    int* cursor = (int*)alloc((size_t)NNODES * 4);
    int* deg = (int*)alloc((size_t)NNODES * 4);
    float* stat = (float*)alloc(NLAYERS * 256 * 4);
    int* local_excl = (int*)alloc((size_t)NNODES * 4);
    int* part = (int*)alloc(SCAN_BLOCKS * 4);
    short* Bf = (short*)alloc((size_t)NLAYERS * 65536 * 2);

    // ---- preprocessing (6 dispatches) ----
    init_kernel<<<(NGRAPHS * 640 + 255) / 256, 256, 0, stream>>>(out, deg, stat);
    deg_kernel<<<(NEDGES + 255) / 256, 256, 0, stream>>>(edge_index, deg);
    scan1<<<SCAN_BLOCKS, 256, 0, stream>>>(deg, local_excl, part);
    scan23<<<SCAN_BLOCKS, 256, 0, stream>>>(part, local_excl, rowptr, cursor);
    edge_fill<<<(NEDGES + 255) / 256, 256, 0, stream>>>(edge_index, edge_weight,
                                                        edge_attr, cursor, epk);
    prep2<<<NSB + EAB + BPB, 256, 0, stream>>>(rowptr, epk, epg, W_bond, b_bond, Ehi,
                                               x, W_atom, b_atom, Hhi, Wl, Wr, Bf);

    // ---- layers: 2 dispatches each (BN folded into consumers) ----
    const short* src = Hhi;
    for (int i = 0; i < NLAYERS; i++) {
        const float* st = (i == 0) ? nullptr : stat + (i - 1) * 256;
        const float* gm = (i == 0) ? nullptr : gamma + (i - 1) * 128;
        const float* bt = (i == 0) ? nullptr : beta + (i - 1) * 128;
        short* Ci = Cbf + (size_t)i * NNODES * 128;
        agg_kernel<<<(NNODES + 15) / 16, 256, 0, stream>>>(src, Ehi, rowptr, epg,
                                                           st, gm, bt, Ahi);
        layer_gemm<<<(NNODES + 127) / 128, 256, 0, stream>>>(
            Ahi, src, st, gm, bt, Bf + (size_t)i * 65536, bl + i * 128, Ci,
            stat + i * 256);
        src = Ci;
    }

    // ---- one pooling kernel for all layers + final h output ----
    pool5<<<(NNODES + 255) / 256, 256, 0, stream>>>(
        Cbf, stat, gamma, beta, batch, out, out + (size_t)NGRAPHS * 640);
}